// Round 24
// baseline (432.933 us; speedup 1.0000x reference)
//
#include <hip/hip_runtime.h>
#include <hip/hip_bf16.h>

typedef __attribute__((ext_vector_type(8))) short short8;
typedef __attribute__((ext_vector_type(4))) float f32x4;
typedef __attribute__((ext_vector_type(4))) int i32x4;
typedef __attribute__((ext_vector_type(2))) int i32x2;
typedef __attribute__((ext_vector_type(4))) unsigned u32x4;

#define NTOK 512
#define NEXP 16
#define TOPK 4
#define HD   2880
#define ID   2880
#define N1   5760   // 2*I
#define NGRP 90     // 32-value groups per row
#define NKT  45     // HD/64 K-steps
#define ROWB 5760   // A row byte stride (HD*2 == ID*2); also B widened row stride

__device__ __forceinline__ void async16(void* lds, const void* g) {
  __builtin_amdgcn_global_load_lds((const __attribute__((address_space(1))) unsigned*)g,
                                   (__attribute__((address_space(3))) unsigned*)lds, 16, 0, 0);
}
__device__ __forceinline__ void async4(void* lds, const void* g) {
  __builtin_amdgcn_global_load_lds((const __attribute__((address_space(1))) unsigned*)g,
                                   (__attribute__((address_space(3))) unsigned*)lds, 4, 0, 0);
}

__device__ __forceinline__ unsigned perm(unsigned hi, unsigned lo, unsigned sel) {
  return __builtin_amdgcn_perm(hi, lo, sel);
}

// ---------------- perm-LUT MXFP4 dequant (bit-exact bf16, scale folded) ----------------
__device__ __forceinline__ u32x4 dq_word4(unsigned p, unsigned hbl, unsigned hbh,
                                          unsigned lbl, unsigned lbh) {
  unsigned ph = p >> 4;
  unsigned il = p  & 0x07070707u, sl = p  & 0x08080808u;
  unsigned ih = ph & 0x07070707u, sh = ph & 0x08080808u;
  unsigned hbL = perm(hbh, hbl, il) | (sl << 4);
  unsigned lbL = perm(lbh, lbl, il);
  unsigned hbH = perm(hbh, hbl, ih) | (sh << 4);
  unsigned lbH = perm(lbh, lbl, ih);
  unsigned mL01 = perm(hbL, lbL, 0x05010400u);
  unsigned mL23 = perm(hbL, lbL, 0x07030602u);
  unsigned mH01 = perm(hbH, lbH, 0x05010400u);
  unsigned mH23 = perm(hbH, lbH, 0x07030602u);
  u32x4 w;
  w.x = perm(mH01, mL01, 0x05040100u);
  w.y = perm(mH01, mL01, 0x07060302u);
  w.z = perm(mH23, mL23, 0x05040100u);
  w.w = perm(mH23, mL23, 0x07060302u);
  return w;
}

__device__ __forceinline__ short8 dq_frag(unsigned pk, int sc) {
  unsigned m7 = (unsigned)((127 - sc) << 7);          // sc in [118,127]
  unsigned mm = m7 | (m7 << 16);
  unsigned e10 = (0x3F00u - m7) << 16;                // entry0 stays exact 0
  unsigned e32 = 0x3FC03F80u - mm;
  unsigned e54 = 0x40404000u - mm;
  unsigned e76 = 0x40C04080u - mm;
  unsigned hbl = perm(e32, e10, 0x07050301u);
  unsigned hbh = perm(e76, e54, 0x07050301u);
  unsigned lbl = perm(e32, e10, 0x06040200u);
  unsigned lbh = perm(e76, e54, 0x06040200u);
  u32x4 w = dq_word4(pk, hbl, hbh, lbl, lbh);
  return __builtin_bit_cast(short8, w);
}

__device__ __forceinline__ unsigned pack8(i32x4 v) {
  return (unsigned)(v.x & 255) | ((unsigned)(v.y & 255) << 8) |
         ((unsigned)(v.z & 255) << 16) | ((unsigned)v.w << 24);
}

// ---------------- RMSNorm (also zeroes cnt) ----------------
__global__ __launch_bounds__(256)
void rmsnorm_k(const float* __restrict__ x, const float* __restrict__ nsc,
               float* __restrict__ tf, __hip_bfloat16* __restrict__ tb,
               int* __restrict__ cnt)
{
  int t = blockIdx.x;
  if (t == 0 && threadIdx.x < NEXP) cnt[threadIdx.x] = 0;
  const float* xr = x + (size_t)t * HD;
  float s = 0.f;
  for (int i = threadIdx.x; i < HD; i += 256) { float v = xr[i]; s += v * v; }
#pragma unroll
  for (int o = 32; o > 0; o >>= 1) s += __shfl_down(s, o);
  __shared__ float red[4];
  if ((threadIdx.x & 63) == 0) red[threadIdx.x >> 6] = s;
  __syncthreads();
  float tot = red[0] + red[1] + red[2] + red[3];
  float rinv = rsqrtf(tot / (float)HD + 1e-5f);
  for (int i = threadIdx.x; i < HD; i += 256) {
    float v = xr[i] * rinv * nsc[i];
    tf[(size_t)t * HD + i] = v;
    tb[(size_t)t * HD + i] = __float2bfloat16(v);
  }
}

// ---------------- Router ----------------
__global__ __launch_bounds__(256)
void router_k(const float* __restrict__ tf, const float* __restrict__ gw,
              const float* __restrict__ gb, float* __restrict__ wpair,
              int* __restrict__ cnt, int* __restrict__ tok_list, int* __restrict__ pair_list)
{
  int t = blockIdx.x;
  int tid = threadIdx.x;
  int e = tid >> 4, l16 = tid & 15;
  const float* tr = tf + (size_t)t * HD;
  float s = 0.f;
  for (int i = l16; i < HD; i += 16) s += tr[i] * gw[e * HD + i];
#pragma unroll
  for (int o = 1; o < 16; o <<= 1) s += __shfl_xor(s, o);
  __shared__ float logits[NEXP];
  if (l16 == 0) logits[e] = s + gb[e];
  __syncthreads();
  if (tid == 0) {
    float v[NEXP];
#pragma unroll
    for (int i = 0; i < NEXP; ++i) v[i] = logits[i];
    int idx[TOPK]; float val[TOPK];
#pragma unroll
    for (int k = 0; k < TOPK; ++k) {
      int bi = 0; float bv = -1e30f;
      for (int i = 0; i < NEXP; ++i) if (v[i] > bv) { bv = v[i]; bi = i; }
      idx[k] = bi; val[k] = bv; v[bi] = -1e30f;
    }
    float mx = val[0], sum = 0.f, w[TOPK];
#pragma unroll
    for (int k = 0; k < TOPK; ++k) { w[k] = __expf(val[k] - mx); sum += w[k]; }
#pragma unroll
    for (int k = 0; k < TOPK; ++k) {
      float wk = w[k] / sum;
      int ee = idx[k];
      int slot = atomicAdd(&cnt[ee], 1);
      tok_list[ee * NTOK + slot]  = t;
      pair_list[ee * NTOK + slot] = t * TOPK + k;
      wpair[t * TOPK + k] = wk;
    }
  }
}

#define FENCE __builtin_amdgcn_sched_barrier(0)

// ---------------- Grouped GEMM: 128M x 128N tile, 4 waves (each 128M x 32N).
// R19/R23-verified counted-vmcnt 2-deep ring; clamped-dup staging handles the
// stage-2 N tail (2880 % 128 != 0); epilogue stores guarded by ncol < NDIM.
template<int STAGE>
__global__ __launch_bounds__(256, 2)
void moe_gemm(const __hip_bfloat16* __restrict__ Asrc,
              const int* __restrict__ Bblk, const int* __restrict__ Bscl,
              const float* __restrict__ Bbias,
              const int* __restrict__ cnt,
              const int* __restrict__ tok_list, const int* __restrict__ pair_list,
              __hip_bfloat16* __restrict__ h_out, float* __restrict__ o_out)
{
  constexpr int NDIM = (STAGE == 1) ? N1 : HD;
  constexpr int NF   = 2;                  // B n-frags per wave (32 cols)
  constexpr int BCH  = 4;                  // B staging instrs per thread
  constexpr int AOFF = 0, BOFF = 16384, SOFF2 = 16384 + 16384;
  constexpr int SLOT2 = SOFF2 + 1024;      // 33792 B per slot
  __shared__ __align__(16) char ring[2 * SLOT2];
  const int e  = blockIdx.z;
  const int ne = cnt[e];
  const int m0 = blockIdx.y * 128;
  if (m0 >= ne) return;
  const int n0 = blockIdx.x * 128;
  const int tid = threadIdx.x;
  const int wave = tid >> 6, lane = tid & 63;
  const int l15 = lane & 15, l4 = lane >> 4;

  const int* glist = (STAGE == 1 ? tok_list : pair_list) + e * NTOK;
  const int* plist = pair_list + e * NTOK;

  // --- A staging sources (linear LDS dest, inverse-swizzled source) ---
  const char* agp[4];
  int alds[4];
#pragma unroll
  for (int c = 0; c < 4; ++c) {
    int o   = c * 4096 + tid * 16;
    int row = o >> 7;
    int scb = (o & 127) ^ ((row & 7) << 4);
    int slot = m0 + row; if (slot > ne - 1) slot = ne - 1;
    agp[c]  = (const char*)Asrc + (size_t)glist[slot] * ROWB + scb;
    alds[c] = AOFF + c * 4096 + wave * 1024;   // wave-uniform; HW adds lane*16
  }
  // --- B staging sources: 128 rows x 128B widened bytes per K-step (clamped dup) ---
  const char* bgp[BCH];
  int blds[BCH];
#pragma unroll
  for (int c = 0; c < BCH; ++c) {
    int idx = c * 256 + tid;
    int row = idx >> 3, ch = idx & 7;
    int br  = n0 + row; if (br > NDIM - 1) br = NDIM - 1;
    bgp[c]  = (const char*)Bblk + (size_t)(e * NDIM + br) * ROWB
              + ((ch ^ (row & 7)) * 16);
    blds[c] = BOFF + c * 4096 + wave * 1024;
  }
  // --- scale staging: 128 rows x 2 ints (clamped dup) ---
  int srow_g = n0 + (tid >> 1); if (srow_g > NDIM - 1) srow_g = NDIM - 1;
  const char* sgp = (const char*)Bscl +
      ((size_t)(e * NDIM + srow_g) * NGRP + (tid & 1)) * 4;
  const int slds = SOFF2 + wave * 256;

  // --- LDS read offsets (each wave: all 8 m-frags, its 32-col B slice) ---
  int aoff[8][2];
#pragma unroll
  for (int mf = 0; mf < 8; ++mf) {
    int row = mf * 16 + l15;
#pragma unroll
    for (int kk = 0; kk < 2; ++kk)
      aoff[mf][kk] = AOFF + row * 128 + ((kk * 64 + l4 * 16) ^ ((row & 7) << 4));
  }
  const int wn = wave * 32;
  int boff[NF][2], soff[NF];
#pragma unroll
  for (int nf = 0; nf < NF; ++nf) {
    int row = wn + nf * 16 + l15;
#pragma unroll
    for (int kk = 0; kk < 2; ++kk)
      boff[nf][kk] = BOFF + row * 128 + ((kk * 64 + l4 * 16) ^ ((row & 7) << 4));
    soff[nf] = SOFF2 + row * 8;
  }

  f32x4 zero = {0.f, 0.f, 0.f, 0.f};
  f32x4 acc[8][NF];
#pragma unroll
  for (int a = 0; a < 8; ++a)
#pragma unroll
    for (int b = 0; b < NF; ++b) acc[a][b] = zero;

#define ISSUE(tt, sl) do { char* sb_ = ring + (sl) * SLOT2; \
    _Pragma("unroll") \
    for (int c_ = 0; c_ < 4; ++c_) async16(sb_ + alds[c_], agp[c_] + (tt) * 128); \
    _Pragma("unroll") \
    for (int c_ = 0; c_ < BCH; ++c_) async16(sb_ + blds[c_], bgp[c_] + (tt) * 128); \
    async4(sb_ + slds, sgp + (tt) * 8); } while (0)

  // --- prologue: tiles 0,1 in flight (18 per-wave issues outstanding) ---
  ISSUE(0, 0);
  ISSUE(1, 1);
  FENCE;

  for (int t = 0; t < NKT; ++t) {
    const int cur = t & 1;
    // tile t landed (its 9 per-wave issues drained); t+1's 9 airborne
    asm volatile("s_waitcnt vmcnt(9)" ::: "memory");
    FENCE;
    __builtin_amdgcn_s_barrier();
    FENCE;

    const char* sb = ring + cur * SLOT2;
    short8 b[NF][2];
#pragma unroll
    for (int nf = 0; nf < NF; ++nf) {
      i32x2 sc = *(const i32x2*)(sb + soff[nf]);
      b[nf][0] = dq_frag(pack8(*(const i32x4*)(sb + boff[nf][0])), sc.x);
      b[nf][1] = dq_frag(pack8(*(const i32x4*)(sb + boff[nf][1])), sc.y);
    }

    __builtin_amdgcn_s_setprio(1);
#pragma unroll
    for (int kk = 0; kk < 2; ++kk) {
#pragma unroll
      for (int mf = 0; mf < 8; ++mf) {
        short8 af = *(const short8*)(sb + aoff[mf][kk]);
#pragma unroll
        for (int nf = 0; nf < NF; ++nf)
          acc[mf][nf] = __builtin_amdgcn_mfma_f32_16x16x32_bf16(af, b[nf][kk], acc[mf][nf], 0, 0, 0);
      }
    }
    __builtin_amdgcn_s_setprio(0);
    FENCE;
    asm volatile("s_waitcnt lgkmcnt(0)" ::: "memory");  // my LDS reads of slot cur done
    FENCE;
    __builtin_amdgcn_s_barrier();                       // all waves done with slot cur
    FENCE;
    int tld = t + 2; if (tld >= NKT) tld = NKT - 1;     // uniform clamped dup issues
    ISSUE(tld, cur);
    FENCE;
  }
#undef ISSUE

  // --- epilogue (stores guarded by ncol < NDIM for the stage-2 tail) ---
  if (STAGE == 1) {
#pragma unroll
    for (int ma = 0; ma < 8; ++ma) {
#pragma unroll
      for (int nf = 0; nf < NF; ++nf) {
        int ncol = n0 + wn + nf * 16 + l15;
        float bias = Bbias[e * NDIM + ncol];
#pragma unroll
        for (int j = 0; j < 4; ++j) {
          float u  = acc[ma][nf][j] + bias;
          float up = __shfl_xor(u, 1);
          int slot = m0 + ma * 16 + l4 * 4 + j;
          if (!(lane & 1) && slot < ne) {
            float g  = fminf(u, 7.f);
            float lv = fminf(fmaxf(up, -7.f), 7.f);
            float hv = g / (1.f + __expf(-1.702f * g)) * (lv + 1.f);
            h_out[(size_t)plist[slot] * ID + (ncol >> 1)] = __float2bfloat16(hv);
          }
        }
      }
    }
  } else {
#pragma unroll
    for (int ma = 0; ma < 8; ++ma) {
#pragma unroll
      for (int nf = 0; nf < NF; ++nf) {
        int ncol = n0 + wn + nf * 16 + l15;
        if (ncol < NDIM) {
          float bias = Bbias[e * NDIM + ncol];
#pragma unroll
          for (int j = 0; j < 4; ++j) {
            int slot = m0 + ma * 16 + l4 * 4 + j;
            if (slot < ne)
              o_out[(size_t)plist[slot] * HD + ncol] = acc[ma][nf][j] + bias;
          }
        }
      }
    }
  }
}

// ---------------- Final combine ----------------
__global__ __launch_bounds__(256)
void final_k(const float* __restrict__ x, const float* __restrict__ obuf,
             const float* __restrict__ wpair, float* __restrict__ out)
{
  int t = blockIdx.x;
  float w0 = wpair[t * 4 + 0], w1 = wpair[t * 4 + 1];
  float w2 = wpair[t * 4 + 2], w3 = wpair[t * 4 + 3];
  const float* o0 = obuf + (size_t)(t * 4) * HD;
  for (int i = threadIdx.x; i < HD; i += 256) {
    float r = x[(size_t)t * HD + i]
            + w0 * o0[i] + w1 * o0[HD + i] + w2 * o0[2 * HD + i] + w3 * o0[3 * HD + i];
    out[(size_t)t * HD + i] = r;
  }
}

extern "C" void kernel_launch(void* const* d_in, const int* in_sizes, int n_in,
                              void* d_out, int out_size, void* d_ws, size_t ws_size,
                              hipStream_t stream)
{
  const float* x    = (const float*)d_in[0];
  const float* nsc  = (const float*)d_in[1];
  const float* gw   = (const float*)d_in[2];
  const float* gb   = (const float*)d_in[3];
  const int*   b1   = (const int*)d_in[4];
  const int*   s1   = (const int*)d_in[5];
  const float* bia1 = (const float*)d_in[6];
  const int*   b2   = (const int*)d_in[7];
  const int*   s2   = (const int*)d_in[8];
  const float* bia2 = (const float*)d_in[9];
  float* out = (float*)d_out;

  char* ws = (char*)d_ws;
  size_t off = 0;
  auto alloc = [&](size_t bytes) {
    char* p = ws + off;
    off = (off + bytes + 255) & ~(size_t)255;
    return p;
  };
  float*           tf    = (float*)alloc((size_t)NTOK * HD * 4);
  __hip_bfloat16*  tb    = (__hip_bfloat16*)alloc((size_t)NTOK * HD * 2);
  __hip_bfloat16*  hbuf  = (__hip_bfloat16*)alloc((size_t)NTOK * TOPK * ID * 2);
  float*           obuf  = (float*)alloc((size_t)NTOK * TOPK * HD * 4);
  float*           wpair = (float*)alloc(NTOK * TOPK * 4);
  int*             cnt   = (int*)alloc(64);
  int*             tokl  = (int*)alloc(NEXP * NTOK * 4);
  int*             pairl = (int*)alloc(NEXP * NTOK * 4);

  rmsnorm_k<<<NTOK, 256, 0, stream>>>(x, nsc, tf, tb, cnt);
  router_k<<<NTOK, 256, 0, stream>>>(tf, gw, gb, wpair, cnt, tokl, pairl);
  moe_gemm<1><<<dim3(N1 / 128, 4, NEXP), 256, 0, stream>>>(tb, b1, s1, bia1, cnt, tokl, pairl, hbuf, nullptr);
  moe_gemm<2><<<dim3((HD + 127) / 128, 4, NEXP), 256, 0, stream>>>(hbuf, b2, s2, bia2, cnt, tokl, pairl, nullptr, obuf);
  final_k<<<NTOK, 256, 0, stream>>>(x, obuf, wpair, out);
}

// Round 25
// 428.676 us; speedup vs baseline: 1.0099x; 1.0099x over previous
//
#include <hip/hip_runtime.h>
#include <hip/hip_bf16.h>

typedef __attribute__((ext_vector_type(8))) short short8;
typedef __attribute__((ext_vector_type(4))) float f32x4;
typedef __attribute__((ext_vector_type(4))) int i32x4;
typedef __attribute__((ext_vector_type(2))) int i32x2;
typedef __attribute__((ext_vector_type(4))) unsigned u32x4;

#define NTOK 512
#define NEXP 16
#define TOPK 4
#define HD   2880
#define ID   2880
#define N1   5760   // 2*I
#define NGRP 90     // 32-value groups per row
#define NKT  45     // HD/64 K-steps
#define ROWB 5760   // A row byte stride (HD*2 == ID*2); also B widened row stride

__device__ __forceinline__ void async16(void* lds, const void* g) {
  __builtin_amdgcn_global_load_lds((const __attribute__((address_space(1))) unsigned*)g,
                                   (__attribute__((address_space(3))) unsigned*)lds, 16, 0, 0);
}
__device__ __forceinline__ void async4(void* lds, const void* g) {
  __builtin_amdgcn_global_load_lds((const __attribute__((address_space(1))) unsigned*)g,
                                   (__attribute__((address_space(3))) unsigned*)lds, 4, 0, 0);
}

__device__ __forceinline__ unsigned perm(unsigned hi, unsigned lo, unsigned sel) {
  return __builtin_amdgcn_perm(hi, lo, sel);
}

// ---------------- perm-LUT MXFP4 dequant (bit-exact bf16, scale folded) ----------------
__device__ __forceinline__ u32x4 dq_word4(unsigned p, unsigned hbl, unsigned hbh,
                                          unsigned lbl, unsigned lbh) {
  unsigned ph = p >> 4;
  unsigned il = p  & 0x07070707u, sl = p  & 0x08080808u;
  unsigned ih = ph & 0x07070707u, sh = ph & 0x08080808u;
  unsigned hbL = perm(hbh, hbl, il) | (sl << 4);
  unsigned lbL = perm(lbh, lbl, il);
  unsigned hbH = perm(hbh, hbl, ih) | (sh << 4);
  unsigned lbH = perm(lbh, lbl, ih);
  unsigned mL01 = perm(hbL, lbL, 0x05010400u);
  unsigned mL23 = perm(hbL, lbL, 0x07030602u);
  unsigned mH01 = perm(hbH, lbH, 0x05010400u);
  unsigned mH23 = perm(hbH, lbH, 0x07030602u);
  u32x4 w;
  w.x = perm(mH01, mL01, 0x05040100u);
  w.y = perm(mH01, mL01, 0x07060302u);
  w.z = perm(mH23, mL23, 0x05040100u);
  w.w = perm(mH23, mL23, 0x07060302u);
  return w;
}

__device__ __forceinline__ short8 dq_frag(unsigned pk, int sc) {
  unsigned m7 = (unsigned)((127 - sc) << 7);          // sc in [118,127]
  unsigned mm = m7 | (m7 << 16);
  unsigned e10 = (0x3F00u - m7) << 16;                // entry0 stays exact 0
  unsigned e32 = 0x3FC03F80u - mm;
  unsigned e54 = 0x40404000u - mm;
  unsigned e76 = 0x40C04080u - mm;
  unsigned hbl = perm(e32, e10, 0x07050301u);
  unsigned hbh = perm(e76, e54, 0x07050301u);
  unsigned lbl = perm(e32, e10, 0x06040200u);
  unsigned lbh = perm(e76, e54, 0x06040200u);
  u32x4 w = dq_word4(pk, hbl, hbh, lbl, lbh);
  return __builtin_bit_cast(short8, w);
}

__device__ __forceinline__ unsigned pack8(i32x4 v) {
  return (unsigned)(v.x & 255) | ((unsigned)(v.y & 255) << 8) |
         ((unsigned)(v.z & 255) << 16) | ((unsigned)v.w << 24);
}

// ---------------- RMSNorm (also zeroes cnt) ----------------
__global__ __launch_bounds__(256)
void rmsnorm_k(const float* __restrict__ x, const float* __restrict__ nsc,
               float* __restrict__ tf, __hip_bfloat16* __restrict__ tb,
               int* __restrict__ cnt)
{
  int t = blockIdx.x;
  if (t == 0 && threadIdx.x < NEXP) cnt[threadIdx.x] = 0;
  const float* xr = x + (size_t)t * HD;
  float s = 0.f;
  for (int i = threadIdx.x; i < HD; i += 256) { float v = xr[i]; s += v * v; }
#pragma unroll
  for (int o = 32; o > 0; o >>= 1) s += __shfl_down(s, o);
  __shared__ float red[4];
  if ((threadIdx.x & 63) == 0) red[threadIdx.x >> 6] = s;
  __syncthreads();
  float tot = red[0] + red[1] + red[2] + red[3];
  float rinv = rsqrtf(tot / (float)HD + 1e-5f);
  for (int i = threadIdx.x; i < HD; i += 256) {
    float v = xr[i] * rinv * nsc[i];
    tf[(size_t)t * HD + i] = v;
    tb[(size_t)t * HD + i] = __float2bfloat16(v);
  }
}

// ---------------- Router ----------------
__global__ __launch_bounds__(256)
void router_k(const float* __restrict__ tf, const float* __restrict__ gw,
              const float* __restrict__ gb, float* __restrict__ wpair,
              int* __restrict__ cnt, int* __restrict__ tok_list, int* __restrict__ pair_list)
{
  int t = blockIdx.x;
  int tid = threadIdx.x;
  int e = tid >> 4, l16 = tid & 15;
  const float* tr = tf + (size_t)t * HD;
  float s = 0.f;
  for (int i = l16; i < HD; i += 16) s += tr[i] * gw[e * HD + i];
#pragma unroll
  for (int o = 1; o < 16; o <<= 1) s += __shfl_xor(s, o);
  __shared__ float logits[NEXP];
  if (l16 == 0) logits[e] = s + gb[e];
  __syncthreads();
  if (tid == 0) {
    float v[NEXP];
#pragma unroll
    for (int i = 0; i < NEXP; ++i) v[i] = logits[i];
    int idx[TOPK]; float val[TOPK];
#pragma unroll
    for (int k = 0; k < TOPK; ++k) {
      int bi = 0; float bv = -1e30f;
      for (int i = 0; i < NEXP; ++i) if (v[i] > bv) { bv = v[i]; bi = i; }
      idx[k] = bi; val[k] = bv; v[bi] = -1e30f;
    }
    float mx = val[0], sum = 0.f, w[TOPK];
#pragma unroll
    for (int k = 0; k < TOPK; ++k) { w[k] = __expf(val[k] - mx); sum += w[k]; }
#pragma unroll
    for (int k = 0; k < TOPK; ++k) {
      float wk = w[k] / sum;
      int ee = idx[k];
      int slot = atomicAdd(&cnt[ee], 1);
      tok_list[ee * NTOK + slot]  = t;
      pair_list[ee * NTOK + slot] = t * TOPK + k;
      wpair[t * TOPK + k] = wk;
    }
  }
}

#define FENCE __builtin_amdgcn_sched_barrier(0)

// ---------------- Grouped GEMM: 128M x BN tile, 4 waves (each 128M x BN/4).
// R19-verified counted-vmcnt 2-deep ring. BN=128 halves per-output LDS traffic
// and VMEM issues (A reads amortized over 2x cols); BN=64 is R19 verbatim.
template<int STAGE, int BN>
__global__ __launch_bounds__(256, (BN == 128 ? 2 : 3))
void moe_gemm(const __hip_bfloat16* __restrict__ Asrc,
              const int* __restrict__ Bblk, const int* __restrict__ Bscl,
              const float* __restrict__ Bbias,
              const int* __restrict__ cnt,
              const int* __restrict__ tok_list, const int* __restrict__ pair_list,
              __hip_bfloat16* __restrict__ h_out, float* __restrict__ o_out)
{
  constexpr int NDIM = (STAGE == 1) ? N1 : HD;
  constexpr int NF   = BN / 64;            // B n-frags per wave
  constexpr int BCH  = BN / 32;            // B staging instrs per thread
  constexpr int BB   = BN * 128;           // B bytes per K-step
  constexpr int AOFF = 0, BOFF = 16384, SOFF2 = 16384 + BB;
  constexpr int SLOT2 = SOFF2 + 1024;
  __shared__ __align__(16) char ring[2 * SLOT2];
  const int e  = blockIdx.z;
  const int ne = cnt[e];
  const int m0 = blockIdx.y * 128;
  if (m0 >= ne) return;
  const int n0 = blockIdx.x * BN;
  const int tid = threadIdx.x;
  const int wave = tid >> 6, lane = tid & 63;
  const int l15 = lane & 15, l4 = lane >> 4;

  const int* glist = (STAGE == 1 ? tok_list : pair_list) + e * NTOK;
  const int* plist = pair_list + e * NTOK;

  // --- A staging sources (linear LDS dest, inverse-swizzled source) ---
  const char* agp[4];
  int alds[4];
#pragma unroll
  for (int c = 0; c < 4; ++c) {
    int o   = c * 4096 + tid * 16;
    int row = o >> 7;
    int scb = (o & 127) ^ ((row & 7) << 4);
    int slot = m0 + row; if (slot > ne - 1) slot = ne - 1;
    agp[c]  = (const char*)Asrc + (size_t)glist[slot] * ROWB + scb;
    alds[c] = AOFF + c * 4096 + wave * 1024;   // wave-uniform; HW adds lane*16
  }
  // --- B staging sources: BN rows x 128B widened bytes per K-step ---
  const char* bgp[BCH];
  int blds[BCH];
#pragma unroll
  for (int c = 0; c < BCH; ++c) {
    int idx = c * 256 + tid;
    int row = idx >> 3, ch = idx & 7;
    bgp[c]  = (const char*)Bblk + (size_t)(e * NDIM + n0 + row) * ROWB
              + ((ch ^ (row & 7)) * 16);
    blds[c] = BOFF + c * 4096 + wave * 1024;
  }
  // --- scale staging: BN rows x 2 ints (BN=64: threads>=128 duplicate) ---
  int sidx = (BN == 128) ? tid : (tid < 128 ? tid : 127);
  const char* sgp = (const char*)Bscl +
      ((size_t)(e * NDIM + n0 + (sidx >> 1)) * NGRP + (sidx & 1)) * 4;
  const int slds = SOFF2 + wave * 256;

  // --- LDS read offsets (each wave: all 8 m-frags, its BN/4-col B slice) ---
  int aoff[8][2];
#pragma unroll
  for (int mf = 0; mf < 8; ++mf) {
    int row = mf * 16 + l15;
#pragma unroll
    for (int kk = 0; kk < 2; ++kk)
      aoff[mf][kk] = AOFF + row * 128 + ((kk * 64 + l4 * 16) ^ ((row & 7) << 4));
  }
  const int wn = wave * (16 * NF);
  int boff[NF][2], soff[NF];
#pragma unroll
  for (int nf = 0; nf < NF; ++nf) {
    int row = wn + nf * 16 + l15;
#pragma unroll
    for (int kk = 0; kk < 2; ++kk)
      boff[nf][kk] = BOFF + row * 128 + ((kk * 64 + l4 * 16) ^ ((row & 7) << 4));
    soff[nf] = SOFF2 + row * 8;
  }

  f32x4 zero = {0.f, 0.f, 0.f, 0.f};
  f32x4 acc[8][NF];
#pragma unroll
  for (int a = 0; a < 8; ++a)
#pragma unroll
    for (int b = 0; b < NF; ++b) acc[a][b] = zero;

#define ISSUE(tt, sl) do { char* sb_ = ring + (sl) * SLOT2; \
    _Pragma("unroll") \
    for (int c_ = 0; c_ < 4; ++c_) async16(sb_ + alds[c_], agp[c_] + (tt) * 128); \
    _Pragma("unroll") \
    for (int c_ = 0; c_ < BCH; ++c_) async16(sb_ + blds[c_], bgp[c_] + (tt) * 128); \
    async4(sb_ + slds, sgp + (tt) * 8); } while (0)

  // --- prologue: tiles 0,1 in flight ---
  ISSUE(0, 0);
  ISSUE(1, 1);
  FENCE;

  for (int t = 0; t < NKT; ++t) {
    const int cur = t & 1;
    // tile t landed (its 4+BCH+1 per-wave issues drained); t+1 airborne
    if constexpr (BN == 128) asm volatile("s_waitcnt vmcnt(9)" ::: "memory");
    else                     asm volatile("s_waitcnt vmcnt(7)" ::: "memory");
    FENCE;
    __builtin_amdgcn_s_barrier();
    FENCE;

    const char* sb = ring + cur * SLOT2;
    short8 b[NF][2];
#pragma unroll
    for (int nf = 0; nf < NF; ++nf) {
      i32x2 sc = *(const i32x2*)(sb + soff[nf]);
      b[nf][0] = dq_frag(pack8(*(const i32x4*)(sb + boff[nf][0])), sc.x);
      b[nf][1] = dq_frag(pack8(*(const i32x4*)(sb + boff[nf][1])), sc.y);
    }

    __builtin_amdgcn_s_setprio(1);
#pragma unroll
    for (int kk = 0; kk < 2; ++kk) {
#pragma unroll
      for (int mf = 0; mf < 8; ++mf) {
        short8 af = *(const short8*)(sb + aoff[mf][kk]);
#pragma unroll
        for (int nf = 0; nf < NF; ++nf)
          acc[mf][nf] = __builtin_amdgcn_mfma_f32_16x16x32_bf16(af, b[nf][kk], acc[mf][nf], 0, 0, 0);
      }
    }
    __builtin_amdgcn_s_setprio(0);
    FENCE;
    asm volatile("s_waitcnt lgkmcnt(0)" ::: "memory");  // my LDS reads of slot cur done
    FENCE;
    __builtin_amdgcn_s_barrier();                       // all waves done with slot cur
    FENCE;
    int tld = t + 2; if (tld >= NKT) tld = NKT - 1;     // uniform clamped dup issues
    ISSUE(tld, cur);
    FENCE;
  }
#undef ISSUE

  // --- epilogue ---
  if (STAGE == 1) {
#pragma unroll
    for (int ma = 0; ma < 8; ++ma) {
#pragma unroll
      for (int nf = 0; nf < NF; ++nf) {
        int ncol = n0 + wn + nf * 16 + l15;
        float bias = Bbias[e * NDIM + ncol];
#pragma unroll
        for (int j = 0; j < 4; ++j) {
          float u  = acc[ma][nf][j] + bias;
          float up = __shfl_xor(u, 1);
          int slot = m0 + ma * 16 + l4 * 4 + j;
          if (!(lane & 1) && slot < ne) {
            float g  = fminf(u, 7.f);
            float lv = fminf(fmaxf(up, -7.f), 7.f);
            float hv = g / (1.f + __expf(-1.702f * g)) * (lv + 1.f);
            h_out[(size_t)plist[slot] * ID + (ncol >> 1)] = __float2bfloat16(hv);
          }
        }
      }
    }
  } else {
#pragma unroll
    for (int ma = 0; ma < 8; ++ma) {
#pragma unroll
      for (int nf = 0; nf < NF; ++nf) {
        int ncol = n0 + wn + nf * 16 + l15;
        float bias = Bbias[e * NDIM + ncol];
#pragma unroll
        for (int j = 0; j < 4; ++j) {
          int slot = m0 + ma * 16 + l4 * 4 + j;
          if (slot < ne)
            o_out[(size_t)plist[slot] * HD + ncol] = acc[ma][nf][j] + bias;
        }
      }
    }
  }
}

// ---------------- Final combine ----------------
__global__ __launch_bounds__(256)
void final_k(const float* __restrict__ x, const float* __restrict__ obuf,
             const float* __restrict__ wpair, float* __restrict__ out)
{
  int t = blockIdx.x;
  float w0 = wpair[t * 4 + 0], w1 = wpair[t * 4 + 1];
  float w2 = wpair[t * 4 + 2], w3 = wpair[t * 4 + 3];
  const float* o0 = obuf + (size_t)(t * 4) * HD;
  for (int i = threadIdx.x; i < HD; i += 256) {
    float r = x[(size_t)t * HD + i]
            + w0 * o0[i] + w1 * o0[HD + i] + w2 * o0[2 * HD + i] + w3 * o0[3 * HD + i];
    out[(size_t)t * HD + i] = r;
  }
}

extern "C" void kernel_launch(void* const* d_in, const int* in_sizes, int n_in,
                              void* d_out, int out_size, void* d_ws, size_t ws_size,
                              hipStream_t stream)
{
  const float* x    = (const float*)d_in[0];
  const float* nsc  = (const float*)d_in[1];
  const float* gw   = (const float*)d_in[2];
  const float* gb   = (const float*)d_in[3];
  const int*   b1   = (const int*)d_in[4];
  const int*   s1   = (const int*)d_in[5];
  const float* bia1 = (const float*)d_in[6];
  const int*   b2   = (const int*)d_in[7];
  const int*   s2   = (const int*)d_in[8];
  const float* bia2 = (const float*)d_in[9];
  float* out = (float*)d_out;

  char* ws = (char*)d_ws;
  size_t off = 0;
  auto alloc = [&](size_t bytes) {
    char* p = ws + off;
    off = (off + bytes + 255) & ~(size_t)255;
    return p;
  };
  float*           tf    = (float*)alloc((size_t)NTOK * HD * 4);
  __hip_bfloat16*  tb    = (__hip_bfloat16*)alloc((size_t)NTOK * HD * 2);
  __hip_bfloat16*  hbuf  = (__hip_bfloat16*)alloc((size_t)NTOK * TOPK * ID * 2);
  float*           obuf  = (float*)alloc((size_t)NTOK * TOPK * HD * 4);
  float*           wpair = (float*)alloc(NTOK * TOPK * 4);
  int*             cnt   = (int*)alloc(64);
  int*             tokl  = (int*)alloc(NEXP * NTOK * 4);
  int*             pairl = (int*)alloc(NEXP * NTOK * 4);

  rmsnorm_k<<<NTOK, 256, 0, stream>>>(x, nsc, tf, tb, cnt);
  router_k<<<NTOK, 256, 0, stream>>>(tf, gw, gb, wpair, cnt, tokl, pairl);
  moe_gemm<1, 128><<<dim3(N1 / 128, 4, NEXP), 256, 0, stream>>>(tb, b1, s1, bia1, cnt, tokl, pairl, hbuf, nullptr);
  moe_gemm<2, 64><<<dim3(HD / 64, 4, NEXP), 256, 0, stream>>>(hbuf, b2, s2, bia2, cnt, tokl, pairl, nullptr, obuf);
  final_k<<<NTOK, 256, 0, stream>>>(x, obuf, wpair, out);
}